// Round 5
// baseline (156.793 us; speedup 1.0000x reference)
//
#include <hip/hip_runtime.h>
#include <hip/hip_bf16.h>

// Sparse 3D neighborhood attention (causal), MI355X. Round 5:
// 3 dispatches. GEMMs consume fp32 x/W directly (in-kernel bf16 cast +
// W transpose during LDS staging); prep pass eliminated.

constexpr int TFR   = 8;
constexpr int SDIM  = 24;
constexpr int NVID  = TFR * SDIM * SDIM;   // 4608
constexpr int NTOK  = NVID + 1;            // 4609
constexpr int NH    = 8;
constexpr int DM    = 512;
constexpr int NJ    = 28;

typedef __attribute__((ext_vector_type(8))) short bf16x8;
typedef __attribute__((ext_vector_type(8))) unsigned short ushort8;
typedef __attribute__((ext_vector_type(4))) float f32x4;

__device__ __forceinline__ float bf2f(unsigned short u) {
    return __uint_as_float((unsigned)u << 16);
}
__device__ __forceinline__ unsigned short f2bf(float f) {
    __hip_bfloat16 h = __float2bfloat16(f);
    return reinterpret_cast<unsigned short&>(h);
}

// ---------------------------------------------------------------------------
// MFMA GEMM from fp32 sources: C = A(MxK fp32) @ W(KxN fp32, k-major).
// BM=BN=128, BK=64, 4 waves 2x2, wave tile 64x64 (4x4 frags 16x16x32 bf16).
// A: read fp32 rows, cvt->bf16, ds_write_b128. B: read fp32 k-major rows,
// transpose during staging (pair-k packed ds_write_b32). LDS pitch 72 shorts
// (144 B rows, 16B-aligned).
// MODE 0: fp32 C += bias. MODE 1 (QKV): n0<512 -> Q fp32 (x0.125 folded),
// else KV bf16. K fixed at 512.
// ---------------------------------------------------------------------------
template<int MODE>
__global__ __launch_bounds__(256)
void gemm_f32src(const float* __restrict__ A,
                 const float* __restrict__ B1,   // Wq / Wout (pitch 512)
                 const float* __restrict__ B2,   // Wkv (pitch 1024) or null
                 float* __restrict__ C, __hip_bfloat16* __restrict__ Cb,
                 int M, int N, const float* __restrict__ bias)
{
    constexpr int BM = 128, BN = 128, BK = 64, PITCH = 72, K = 512;
    __shared__ short As[BM * PITCH];
    __shared__ short Bs[BN * PITCH];

    const int tid  = threadIdx.x;
    const int m0   = blockIdx.x * BM;
    const int n0   = blockIdx.y * BN;
    const int lane = tid & 63;
    const int wave = tid >> 6;
    const int wm   = (wave >> 1) * 64;
    const int wn   = (wave & 1) * 64;
    const int col  = lane & 15;
    const int quad = lane >> 4;

    // B source select (block-uniform; BN=128 never straddles the 512 split)
    const float* Bsrc; int bpitch, col0;
    if (MODE == 1 && n0 >= 512) { Bsrc = B2; bpitch = 1024; col0 = n0 - 512; }
    else                        { Bsrc = B1; bpitch = 512;  col0 = n0; }

    f32x4 acc[4][4] = {};

    for (int k0 = 0; k0 < K; k0 += BK) {
        // ---- stage A: 128 m x 64 k; fp32 read -> bf16 -> ds_write_b128 ----
        #pragma unroll
        for (int r = 0; r < 4; ++r) {
            const int m  = (tid >> 3) + r * 32;
            const int k8 = (tid & 7) * 8;
            const int gm = (m0 + m < M) ? (m0 + m) : (M - 1);
            const float4 f0 = *(const float4*)(A + (size_t)gm * K + k0 + k8);
            const float4 f1 = *(const float4*)(A + (size_t)gm * K + k0 + k8 + 4);
            unsigned short v[8] = { f2bf(f0.x), f2bf(f0.y), f2bf(f0.z), f2bf(f0.w),
                                    f2bf(f1.x), f2bf(f1.y), f2bf(f1.z), f2bf(f1.w) };
            *(ushort8*)(&As[m * PITCH + k8]) = *(const ushort8*)v;
        }
        // ---- stage B: transpose W[k][n] -> Bs[n][k], pair-k b32 writes ----
        #pragma unroll
        for (int r = 0; r < 4; ++r) {
            const int p = (tid >> 4) + (r >> 1) * 16;        // k-pair 0..31
            const int n = (tid & 15) * 4 + (r & 1) * 64;     // 0..124
            const float4 f0 = *(const float4*)(Bsrc + (size_t)(k0 + 2 * p)     * bpitch + col0 + n);
            const float4 f1 = *(const float4*)(Bsrc + (size_t)(k0 + 2 * p + 1) * bpitch + col0 + n);
            const float e0[4] = { f0.x, f0.y, f0.z, f0.w };
            const float e1[4] = { f1.x, f1.y, f1.z, f1.w };
            #pragma unroll
            for (int e = 0; e < 4; ++e) {
                const unsigned pk = (unsigned)f2bf(e0[e]) | ((unsigned)f2bf(e1[e]) << 16);
                *(unsigned*)(&Bs[(n + e) * PITCH + 2 * p]) = pk;
            }
        }
        __syncthreads();

        #pragma unroll
        for (int ks = 0; ks < 2; ++ks) {
            bf16x8 af[4], bfr[4];
            #pragma unroll
            for (int mt = 0; mt < 4; ++mt)
                af[mt] = *(const bf16x8*)(&As[(wm + mt * 16 + col) * PITCH + ks * 32 + quad * 8]);
            #pragma unroll
            for (int nt = 0; nt < 4; ++nt)
                bfr[nt] = *(const bf16x8*)(&Bs[(wn + nt * 16 + col) * PITCH + ks * 32 + quad * 8]);
            #pragma unroll
            for (int mt = 0; mt < 4; ++mt)
                #pragma unroll
                for (int nt = 0; nt < 4; ++nt)
                    acc[mt][nt] = __builtin_amdgcn_mfma_f32_16x16x32_bf16(
                        af[mt], bfr[nt], acc[mt][nt], 0, 0, 0);
        }
        __syncthreads();
    }

    // epilogue: D mapping col=lane&15, row=quad*4+reg [m89-verified]
    const bool isQ = (MODE == 1) && (n0 < 512);
    #pragma unroll
    for (int mt = 0; mt < 4; ++mt) {
        #pragma unroll
        for (int r = 0; r < 4; ++r) {
            const int row = m0 + wm + mt * 16 + quad * 4 + r;
            if (row >= M) continue;
            #pragma unroll
            for (int nt = 0; nt < 4; ++nt) {
                const int cg = n0 + wn + nt * 16 + col;
                float v = acc[mt][nt][r];
                if (MODE == 0) {
                    if (bias) v += bias[cg];
                    C[(size_t)row * N + cg] = v;
                } else if (isQ) {
                    C[(size_t)row * 512 + cg] = v * 0.125f;   // q scale folded
                } else {
                    Cb[(size_t)row * 1024 + (cg - 512)] = __float2bfloat16(v);
                }
            }
        }
    }
}

// ---------------------------------------------------------------------------
// Attention: one wave per query; 4 queries per block. Lane l = g*8+s owns
// columns [l*8, l*8+8). Q fp32 (pre-scaled), KVb bf16 [K(512)|V(512)],
// output O fp32.
// ---------------------------------------------------------------------------
__global__ __launch_bounds__(256)
void attn_v2(const float* __restrict__ Q, const __hip_bfloat16* __restrict__ KVb,
             float* __restrict__ O,
             const float* __restrict__ W_th,
             const float* __restrict__ ax1, const float* __restrict__ ax2,
             const float* __restrict__ ax3)
{
    __shared__ float attn_s[4][NH * NJ];
    __shared__ float mixed_s[4][NH * NJ];

    const int tid  = threadIdx.x;
    const int wave = tid >> 6;
    const int lane = tid & 63;
    const int g    = lane >> 3;
    const int s    = lane & 7;
    const int i    = __builtin_amdgcn_readfirstlane(blockIdx.x * 4 + (tid >> 6));
    const int qrow = i + 1;

    const int t  = i / (SDIM * SDIM);
    const int rm = i % (SDIM * SDIM);
    const int y  = rm / SDIM;
    const int x  = rm % SDIM;

    float qf[8];
    {
        const float4 q0 = *(const float4*)(Q + (size_t)qrow * DM + lane * 8);
        const float4 q1 = *(const float4*)(Q + (size_t)qrow * DM + lane * 8 + 4);
        qf[0] = q0.x; qf[1] = q0.y; qf[2] = q0.z; qf[3] = q0.w;
        qf[4] = q1.x; qf[5] = q1.y; qf[6] = q1.z; qf[7] = q1.w;
    }
    float a1[3], a2[3], a3[3];
    #pragma unroll
    for (int d = 0; d < 3; ++d) {
        a1[d] = ax1[d * NH + g];
        a2[d] = ax2[d * NH + g];
        a3[d] = ax3[d * NH + g];
    }

    float sim[NJ];
    #pragma unroll
    for (int j = 0; j < NJ; ++j) {
        int row; bool valid; float bias;
        if (j == 0) { row = 0; valid = true; bias = 0.f; }
        else {
            const int jp = j - 1;
            const int di = jp / 9, dj = (jp / 3) % 3, dk = jp % 3;
            const int tt = t + di - 2, yy = y + dj - 2, xx = x + dk - 2;
            valid = (tt >= 0) && (yy >= 0) && (xx >= 0);
            row = 1 + tt * SDIM * SDIM + yy * SDIM + xx;
            bias = a1[di] + a2[dj] + a3[dk];
        }
        if (valid) {
            const ushort8 kv = *(const ushort8*)(KVb + (size_t)row * 1024 + lane * 8);
            float p = 0.f;
            #pragma unroll
            for (int e = 0; e < 8; ++e) p += bf2f(kv[e]) * qf[e];
            p += __shfl_xor(p, 1);
            p += __shfl_xor(p, 2);
            p += __shfl_xor(p, 4);
            sim[j] = p + bias;
        } else {
            sim[j] = -1e30f;
        }
    }

    float m = -1e30f;
    #pragma unroll
    for (int j = 0; j < NJ; ++j) m = fmaxf(m, sim[j]);
    float ssum = 0.f;
    #pragma unroll
    for (int j = 0; j < NJ; ++j) { sim[j] = __expf(sim[j] - m); ssum += sim[j]; }
    const float inv = 1.f / ssum;
    #pragma unroll
    for (int j = 0; j < NJ; ++j) sim[j] *= inv;

    if (s == 0) {
        #pragma unroll
        for (int u = 0; u < 7; ++u) {
            f32x4 v4 = { sim[4*u], sim[4*u+1], sim[4*u+2], sim[4*u+3] };
            *(f32x4*)(&attn_s[wave][g * NJ + 4 * u]) = v4;
        }
    }
    __syncthreads();

    if (tid < NH * NJ) {
        const int h = tid / NJ, j = tid % NJ;
        #pragma unroll
        for (int q = 0; q < 4; ++q) {
            float acc = 0.f;
            #pragma unroll
            for (int gg = 0; gg < NH; ++gg)
                acc += W_th[h * NH + gg] * attn_s[q][gg * NJ + j];
            mixed_s[q][h * NJ + j] = acc;
        }
    }
    __syncthreads();

    float acc8[8] = {};
    #pragma unroll
    for (int j = 0; j < NJ; ++j) {
        int row; bool valid;
        if (j == 0) { row = 0; valid = true; }
        else {
            const int jp = j - 1;
            const int di = jp / 9, dj = (jp / 3) % 3, dk = jp % 3;
            const int tt = t + di - 2, yy = y + dj - 2, xx = x + dk - 2;
            valid = (tt >= 0) && (yy >= 0) && (xx >= 0);
            row = 1 + tt * SDIM * SDIM + yy * SDIM + xx;
        }
        if (valid) {
            const ushort8 vv = *(const ushort8*)(KVb + (size_t)row * 1024 + 512 + lane * 8);
            const float w = mixed_s[wave][g * NJ + j];
            #pragma unroll
            for (int e = 0; e < 8; ++e) acc8[e] += w * bf2f(vv[e]);
        }
    }

    float4 o0 = { acc8[0], acc8[1], acc8[2], acc8[3] };
    float4 o1 = { acc8[4], acc8[5], acc8[6], acc8[7] };
    *(float4*)(O + (size_t)qrow * DM + lane * 8)     = o0;
    *(float4*)(O + (size_t)qrow * DM + lane * 8 + 4) = o1;

    if (i == 0) {   // BOS output row = V row 0 (wave-uniform branch)
        const ushort8 vb = *(const ushort8*)(KVb + 512 + lane * 8);
        float4 b0 = { bf2f(vb[0]), bf2f(vb[1]), bf2f(vb[2]), bf2f(vb[3]) };
        float4 b1 = { bf2f(vb[4]), bf2f(vb[5]), bf2f(vb[6]), bf2f(vb[7]) };
        *(float4*)(O + lane * 8)     = b0;
        *(float4*)(O + lane * 8 + 4) = b1;
    }
}

// ---------------------------------------------------------------------------
extern "C" void kernel_launch(void* const* d_in, const int* in_sizes, int n_in,
                              void* d_out, int out_size, void* d_ws, size_t ws_size,
                              hipStream_t stream)
{
    const float* x    = (const float*)d_in[0];
    const float* Wq   = (const float*)d_in[1];
    const float* Wkv  = (const float*)d_in[2];
    const float* W_th = (const float*)d_in[3];
    const float* Wout = (const float*)d_in[4];
    const float* bout = (const float*)d_in[5];
    const float* ax1  = (const float*)d_in[6];
    const float* ax2  = (const float*)d_in[7];
    const float* ax3  = (const float*)d_in[8];
    float* out = (float*)d_out;

    char* p = (char*)d_ws;
    float* Qf = (float*)p;                       p += (size_t)NTOK * DM * 4;
    __hip_bfloat16* KVb = (__hip_bfloat16*)p;    p += (size_t)NTOK * 2 * DM * 2;
    float* Of = (float*)p;                       p += (size_t)NTOK * DM * 4;

    const dim3 blk(256);
    const int mtiles = (NTOK + 127) / 128;   // 37

    // QKV: 4609 x 1536 x 512 from fp32 x, Wq, Wkv (Q fp32 scaled | KV bf16)
    gemm_f32src<1><<<dim3(mtiles, 12), blk, 0, stream>>>(
        x, Wq, Wkv, Qf, KVb, NTOK, 3 * DM, nullptr);

    attn_v2<<<dim3(NVID / 4), blk, 0, stream>>>(Qf, KVb, Of, W_th, ax1, ax2, ax3);

    // out-proj: 4609 x 512 x 512 (+bias), fp32 sources
    gemm_f32src<0><<<dim3(mtiles, 4), blk, 0, stream>>>(
        Of, Wout, nullptr, out, nullptr, NTOK, DM, bout);
}

// Round 6
// 133.709 us; speedup vs baseline: 1.1726x; 1.1726x over previous
//
#include <hip/hip_runtime.h>
#include <hip/hip_bf16.h>

// Sparse 3D neighborhood attention (causal), MI355X. Round 6:
// R4 GEMM base; x-cast absorbed into QKV A-staging; weights-only prep;
// out-proj GEMM at 64x64 tiles for 2.3 blocks/CU.

constexpr int TFR   = 8;
constexpr int SDIM  = 24;
constexpr int NVID  = TFR * SDIM * SDIM;   // 4608
constexpr int NTOK  = NVID + 1;            // 4609
constexpr int NH    = 8;
constexpr int DM    = 512;
constexpr int NJ    = 28;

typedef __attribute__((ext_vector_type(8))) short bf16x8;
typedef __attribute__((ext_vector_type(8))) unsigned short ushort8;
typedef __attribute__((ext_vector_type(4))) float f32x4;

typedef const __attribute__((address_space(1))) unsigned int* gas_ptr;
typedef __attribute__((address_space(3))) unsigned int* las_ptr;

__device__ __forceinline__ float bf2f(unsigned short u) {
    return __uint_as_float((unsigned)u << 16);
}
__device__ __forceinline__ unsigned short f2bf(float f) {
    __hip_bfloat16 h = __float2bfloat16(f);
    return reinterpret_cast<unsigned short&>(h);
}

// ---------------------------------------------------------------------------
// prep: transpose+cast Wq/Wkv (one 1536x512 bf16 buffer) and Wout. 1024 blocks.
// ---------------------------------------------------------------------------
__global__ __launch_bounds__(256)
void prep_w(const float* __restrict__ Wq, const float* __restrict__ Wkv,
            const float* __restrict__ Wout,
            __hip_bfloat16* __restrict__ Wqkvt, __hip_bfloat16* __restrict__ Woutt)
{
    __shared__ float t[32][33];
    const int tid = threadIdx.x;
    int tb = blockIdx.x;
    const float* W; __hip_bfloat16* Wt; int Nd, tX, rowOff;
    if (tb < 256)      { W = Wq;   Wt = Wqkvt; Nd = 512;  tX = 16; rowOff = 0;   }
    else if (tb < 768) { tb -= 256; W = Wkv;  Wt = Wqkvt; Nd = 1024; tX = 32; rowOff = 512; }
    else               { tb -= 768; W = Wout; Wt = Woutt; Nd = 512;  tX = 16; rowOff = 0;   }
    const int n0 = (tb % tX) * 32, k0 = (tb / tX) * 32;
    const int r  = tid >> 3;
    const int c4 = (tid & 7) * 4;
    const float4 v = *(const float4*)(W + (size_t)(k0 + r) * Nd + n0 + c4);
    t[r][c4 + 0] = v.x; t[r][c4 + 1] = v.y; t[r][c4 + 2] = v.z; t[r][c4 + 3] = v.w;
    __syncthreads();
    #pragma unroll
    for (int j = 0; j < 4; ++j)
        Wt[(size_t)(rowOff + n0 + r) * 512 + k0 + c4 + j] = __float2bfloat16(t[c4 + j][r]);
}

// ---------------------------------------------------------------------------
// QKV GEMM: C = x(Mx512 fp32) @ Wqkvt(1536x512 bf16)^T. BM=BN=128, BK=64,
// 4 waves 2x2, wave tile 64x64. A: fp32 read -> cvt -> padded LDS (pitch 72,
// 2-way max = free). B: bf16 global_load_lds w/ XOR source swizzle (linear
// LDS, DMA constraint). Epilogue: n0<512 -> Q fp32 (x0.125), else KV bf16.
// ---------------------------------------------------------------------------
__global__ __launch_bounds__(256)
void gemm_qkv(const float* __restrict__ A, const __hip_bfloat16* __restrict__ Bt,
              float* __restrict__ Cq, __hip_bfloat16* __restrict__ Ckv, int M)
{
    constexpr int BM = 128, BN = 128, BK = 64, PITCH = 72, K = 512;
    __shared__ short As[BM * PITCH];
    __shared__ __align__(16) short Bs[BN * BK];

    const int tid  = threadIdx.x;
    const int m0   = blockIdx.x * BM;
    const int n0   = blockIdx.y * BN;
    const int lane = tid & 63;
    const int wave = tid >> 6;
    const int wm   = (wave >> 1) * 64;
    const int wn   = (wave & 1) * 64;
    const int col  = lane & 15;
    const int quad = lane >> 4;

    f32x4 acc[4][4] = {};

    for (int k0 = 0; k0 < K; k0 += BK) {
        // ---- stage B first (DMA, fire-and-forget until barrier) ----------
        #pragma unroll
        for (int it = 0; it < 4; ++it) {
            const int idx = it * 256 + tid;
            const int r   = idx >> 3;
            const int u   = (idx & 7) ^ (r & 7);
            const __hip_bfloat16* gp = Bt + (size_t)(n0 + r) * K + k0 + u * 8;
            __builtin_amdgcn_global_load_lds(
                (gas_ptr)gp, (las_ptr)&Bs[(it * 256 + wave * 64) * 8], 16, 0, 0);
        }
        // ---- stage A: fp32 read -> bf16 -> ds_write_b128 -----------------
        #pragma unroll
        for (int r = 0; r < 4; ++r) {
            const int m  = (tid >> 3) + r * 32;
            const int k8 = (tid & 7) * 8;
            const int gm = (m0 + m < M) ? (m0 + m) : (M - 1);
            const float4 f0 = *(const float4*)(A + (size_t)gm * K + k0 + k8);
            const float4 f1 = *(const float4*)(A + (size_t)gm * K + k0 + k8 + 4);
            unsigned short v[8] = { f2bf(f0.x), f2bf(f0.y), f2bf(f0.z), f2bf(f0.w),
                                    f2bf(f1.x), f2bf(f1.y), f2bf(f1.z), f2bf(f1.w) };
            *(ushort8*)(&As[m * PITCH + k8]) = *(const ushort8*)v;
        }
        __syncthreads();

        #pragma unroll
        for (int ks = 0; ks < 2; ++ks) {
            bf16x8 af[4], bfr[4];
            #pragma unroll
            for (int mt = 0; mt < 4; ++mt)
                af[mt] = *(const bf16x8*)(&As[(wm + mt * 16 + col) * PITCH + ks * 32 + quad * 8]);
            #pragma unroll
            for (int nt = 0; nt < 4; ++nt) {
                const int r = wn + nt * 16 + col;
                const int u = (ks * 4 + quad) ^ (r & 7);
                bfr[nt] = *(const bf16x8*)(&Bs[r * BK + u * 8]);
            }
            #pragma unroll
            for (int mt = 0; mt < 4; ++mt)
                #pragma unroll
                for (int nt = 0; nt < 4; ++nt)
                    acc[mt][nt] = __builtin_amdgcn_mfma_f32_16x16x32_bf16(
                        af[mt], bfr[nt], acc[mt][nt], 0, 0, 0);
        }
        __syncthreads();
    }

    const bool isQ = (n0 < 512);
    #pragma unroll
    for (int mt = 0; mt < 4; ++mt) {
        #pragma unroll
        for (int r = 0; r < 4; ++r) {
            const int row = m0 + wm + mt * 16 + quad * 4 + r;
            if (row >= M) continue;
            #pragma unroll
            for (int nt = 0; nt < 4; ++nt) {
                const int cg = n0 + wn + nt * 16 + col;
                const float v = acc[mt][nt][r];
                if (isQ) Cq[(size_t)row * 512 + cg] = v * 0.125f;
                else     Ckv[(size_t)row * 1024 + (cg - 512)] = __float2bfloat16(v);
            }
        }
    }
}

// ---------------------------------------------------------------------------
// out-proj GEMM: C = Ob(Mx512 bf16) @ Woutt(512x512 bf16)^T + bias.
// BM=BN=64 (584 blocks = 2.3/CU), 4 waves 2x2, wave tile 32x32. Both operands
// via global_load_lds + XOR swizzle.
// ---------------------------------------------------------------------------
__global__ __launch_bounds__(256)
void gemm_out(const __hip_bfloat16* __restrict__ A, const __hip_bfloat16* __restrict__ Bt,
              float* __restrict__ C, int M, const float* __restrict__ bias)
{
    constexpr int BM = 64, BN = 64, BK = 64, K = 512;
    __shared__ __align__(16) short As[BM * BK];
    __shared__ __align__(16) short Bs[BN * BK];

    const int tid  = threadIdx.x;
    const int m0   = blockIdx.x * BM;
    const int n0   = blockIdx.y * BN;
    const int lane = tid & 63;
    const int wave = tid >> 6;
    const int wm   = (wave >> 1) * 32;
    const int wn   = (wave & 1) * 32;
    const int col  = lane & 15;
    const int quad = lane >> 4;

    f32x4 acc[2][2] = {};

    for (int k0 = 0; k0 < K; k0 += BK) {
        #pragma unroll
        for (int it = 0; it < 2; ++it) {
            const int idx = it * 256 + tid;
            const int r   = idx >> 3;
            const int u   = (idx & 7) ^ (r & 7);
            const __hip_bfloat16* gp = A + (size_t)(m0 + r) * K + k0 + u * 8;
            __builtin_amdgcn_global_load_lds(
                (gas_ptr)gp, (las_ptr)&As[(it * 256 + wave * 64) * 8], 16, 0, 0);
        }
        #pragma unroll
        for (int it = 0; it < 2; ++it) {
            const int idx = it * 256 + tid;
            const int r   = idx >> 3;
            const int u   = (idx & 7) ^ (r & 7);
            const __hip_bfloat16* gp = Bt + (size_t)(n0 + r) * K + k0 + u * 8;
            __builtin_amdgcn_global_load_lds(
                (gas_ptr)gp, (las_ptr)&Bs[(it * 256 + wave * 64) * 8], 16, 0, 0);
        }
        __syncthreads();

        #pragma unroll
        for (int ks = 0; ks < 2; ++ks) {
            bf16x8 af[2], bfr[2];
            #pragma unroll
            for (int mt = 0; mt < 2; ++mt) {
                const int r = wm + mt * 16 + col;
                const int u = (ks * 4 + quad) ^ (r & 7);
                af[mt] = *(const bf16x8*)(&As[r * BK + u * 8]);
            }
            #pragma unroll
            for (int nt = 0; nt < 2; ++nt) {
                const int r = wn + nt * 16 + col;
                const int u = (ks * 4 + quad) ^ (r & 7);
                bfr[nt] = *(const bf16x8*)(&Bs[r * BK + u * 8]);
            }
            #pragma unroll
            for (int mt = 0; mt < 2; ++mt)
                #pragma unroll
                for (int nt = 0; nt < 2; ++nt)
                    acc[mt][nt] = __builtin_amdgcn_mfma_f32_16x16x32_bf16(
                        af[mt], bfr[nt], acc[mt][nt], 0, 0, 0);
        }
        __syncthreads();
    }

    #pragma unroll
    for (int mt = 0; mt < 2; ++mt) {
        #pragma unroll
        for (int r = 0; r < 4; ++r) {
            const int row = m0 + wm + mt * 16 + quad * 4 + r;
            if (row >= M) continue;
            #pragma unroll
            for (int nt = 0; nt < 2; ++nt) {
                const int cg = n0 + wn + nt * 16 + col;
                C[(size_t)row * 512 + cg] = acc[mt][nt][r] + bias[cg];
            }
        }
    }
}

// ---------------------------------------------------------------------------
// Attention: one wave per query; 4 queries per block. Lane l = g*8+s owns
// columns [l*8, l*8+8). Q fp32 (pre-scaled), KVb bf16 [K(512)|V(512)], O bf16.
// ---------------------------------------------------------------------------
__global__ __launch_bounds__(256)
void attn_v2(const float* __restrict__ Q, const __hip_bfloat16* __restrict__ KVb,
             __hip_bfloat16* __restrict__ O,
             const float* __restrict__ W_th,
             const float* __restrict__ ax1, const float* __restrict__ ax2,
             const float* __restrict__ ax3)
{
    __shared__ float attn_s[4][NH * NJ];
    __shared__ float mixed_s[4][NH * NJ];

    const int tid  = threadIdx.x;
    const int wave = tid >> 6;
    const int lane = tid & 63;
    const int g    = lane >> 3;
    const int s    = lane & 7;
    const int i    = __builtin_amdgcn_readfirstlane(blockIdx.x * 4 + (tid >> 6));
    const int qrow = i + 1;

    const int t  = i / (SDIM * SDIM);
    const int rm = i % (SDIM * SDIM);
    const int y  = rm / SDIM;
    const int x  = rm % SDIM;

    float qf[8];
    {
        const float4 q0 = *(const float4*)(Q + (size_t)qrow * DM + lane * 8);
        const float4 q1 = *(const float4*)(Q + (size_t)qrow * DM + lane * 8 + 4);
        qf[0] = q0.x; qf[1] = q0.y; qf[2] = q0.z; qf[3] = q0.w;
        qf[4] = q1.x; qf[5] = q1.y; qf[6] = q1.z; qf[7] = q1.w;
    }
    float a1[3], a2[3], a3[3];
    #pragma unroll
    for (int d = 0; d < 3; ++d) {
        a1[d] = ax1[d * NH + g];
        a2[d] = ax2[d * NH + g];
        a3[d] = ax3[d * NH + g];
    }

    float sim[NJ];
    #pragma unroll
    for (int j = 0; j < NJ; ++j) {
        int row; bool valid; float bias;
        if (j == 0) { row = 0; valid = true; bias = 0.f; }
        else {
            const int jp = j - 1;
            const int di = jp / 9, dj = (jp / 3) % 3, dk = jp % 3;
            const int tt = t + di - 2, yy = y + dj - 2, xx = x + dk - 2;
            valid = (tt >= 0) && (yy >= 0) && (xx >= 0);
            row = 1 + tt * SDIM * SDIM + yy * SDIM + xx;
            bias = a1[di] + a2[dj] + a3[dk];
        }
        if (valid) {
            const ushort8 kv = *(const ushort8*)(KVb + (size_t)row * 1024 + lane * 8);
            float p = 0.f;
            #pragma unroll
            for (int e = 0; e < 8; ++e) p += bf2f(kv[e]) * qf[e];
            p += __shfl_xor(p, 1);
            p += __shfl_xor(p, 2);
            p += __shfl_xor(p, 4);
            sim[j] = p + bias;
        } else {
            sim[j] = -1e30f;
        }
    }

    float m = -1e30f;
    #pragma unroll
    for (int j = 0; j < NJ; ++j) m = fmaxf(m, sim[j]);
    float ssum = 0.f;
    #pragma unroll
    for (int j = 0; j < NJ; ++j) { sim[j] = __expf(sim[j] - m); ssum += sim[j]; }
    const float inv = 1.f / ssum;
    #pragma unroll
    for (int j = 0; j < NJ; ++j) sim[j] *= inv;

    if (s == 0) {
        #pragma unroll
        for (int u = 0; u < 7; ++u) {
            f32x4 v4 = { sim[4*u], sim[4*u+1], sim[4*u+2], sim[4*u+3] };
            *(f32x4*)(&attn_s[wave][g * NJ + 4 * u]) = v4;
        }
    }
    __syncthreads();

    if (tid < NH * NJ) {
        const int h = tid / NJ, j = tid % NJ;
        #pragma unroll
        for (int q = 0; q < 4; ++q) {
            float acc = 0.f;
            #pragma unroll
            for (int gg = 0; gg < NH; ++gg)
                acc += W_th[h * NH + gg] * attn_s[q][gg * NJ + j];
            mixed_s[q][h * NJ + j] = acc;
        }
    }
    __syncthreads();

    float acc8[8] = {};
    #pragma unroll
    for (int j = 0; j < NJ; ++j) {
        int row; bool valid;
        if (j == 0) { row = 0; valid = true; }
        else {
            const int jp = j - 1;
            const int di = jp / 9, dj = (jp / 3) % 3, dk = jp % 3;
            const int tt = t + di - 2, yy = y + dj - 2, xx = x + dk - 2;
            valid = (tt >= 0) && (yy >= 0) && (xx >= 0);
            row = 1 + tt * SDIM * SDIM + yy * SDIM + xx;
        }
        if (valid) {
            const ushort8 vv = *(const ushort8*)(KVb + (size_t)row * 1024 + 512 + lane * 8);
            const float w = mixed_s[wave][g * NJ + j];
            #pragma unroll
            for (int e = 0; e < 8; ++e) acc8[e] += w * bf2f(vv[e]);
        }
    }

    unsigned short o[8];
    #pragma unroll
    for (int e = 0; e < 8; ++e) o[e] = f2bf(acc8[e]);
    *(ushort8*)(O + (size_t)qrow * DM + lane * 8) = *(const ushort8*)o;

    if (i == 0) {
        const ushort8 vb = *(const ushort8*)(KVb + 512 + lane * 8);
        *(ushort8*)(O + lane * 8) = vb;
    }
}

// ---------------------------------------------------------------------------
extern "C" void kernel_launch(void* const* d_in, const int* in_sizes, int n_in,
                              void* d_out, int out_size, void* d_ws, size_t ws_size,
                              hipStream_t stream)
{
    const float* x    = (const float*)d_in[0];
    const float* Wq   = (const float*)d_in[1];
    const float* Wkv  = (const float*)d_in[2];
    const float* W_th = (const float*)d_in[3];
    const float* Wout = (const float*)d_in[4];
    const float* bout = (const float*)d_in[5];
    const float* ax1  = (const float*)d_in[6];
    const float* ax2  = (const float*)d_in[7];
    const float* ax3  = (const float*)d_in[8];
    float* out = (float*)d_out;

    char* p = (char*)d_ws;
    float* Qf = (float*)p;                       p += (size_t)NTOK * DM * 4;
    __hip_bfloat16* KVb   = (__hip_bfloat16*)p;  p += (size_t)NTOK * 2 * DM * 2;
    __hip_bfloat16* Ob    = (__hip_bfloat16*)p;  p += (size_t)NTOK * DM * 2;
    __hip_bfloat16* Wqkvt = (__hip_bfloat16*)p;  p += (size_t)3 * DM * DM * 2;
    __hip_bfloat16* Woutt = (__hip_bfloat16*)p;  p += (size_t)DM * DM * 2;

    const dim3 blk(256);
    const int mtiles128 = (NTOK + 127) / 128;   // 37
    const int mtiles64  = (NTOK + 63) / 64;     // 73

    prep_w<<<1024, blk, 0, stream>>>(Wq, Wkv, Wout, Wqkvt, Woutt);

    gemm_qkv<<<dim3(mtiles128, 12), blk, 0, stream>>>(x, Wqkvt, Qf, KVb, NTOK);

    attn_v2<<<dim3(NVID / 4), blk, 0, stream>>>(Qf, KVb, Ob, W_th, ax1, ax2, ax3);

    gemm_out<<<dim3(mtiles64, 8), blk, 0, stream>>>(Ob, Woutt, out, NTOK, bout);
}